// Round 7
// baseline (29109.317 us; speedup 1.0000x reference)
//
#include <hip/hip_runtime.h>
#include <hip/hip_bf16.h>

using bf16   = __bf16;
using bf16x8 = __attribute__((ext_vector_type(8))) __bf16;
using f32x4  = __attribute__((ext_vector_type(4))) float;
using u32x4  = __attribute__((ext_vector_type(4))) unsigned int;

#define TSTEPS 255
// element (bf16) counts
#define UNITE  512              // elements per 1KiB MFMA fragment unit
#define HPAR   (16*16*512)      // one (parity,hi-or-lo) h plane: 16 bq x 16 kb units
#define WA_UNITS_DIR (128*24)
#define WB_UNITS_DIR (128*32)
#define WC_UNITS_DIR (16*16)

#define MFMA(acc, a, b) acc = __builtin_amdgcn_mfma_f32_16x16x32_bf16((a), (b), (acc), 0, 0, 0)

__device__ __forceinline__ float sigmoidf_(float x) { return 1.f / (1.f + __expf(-x)); }
__device__ __forceinline__ float tanhf_(float x) {
    float e = __expf(-2.f * fabsf(x));
    float t = (1.f - e) / (1.f + e);
    return copysignf(t, x);
}

// async global->LDS 16B/lane (1 KiB/wave per call). LDS dest is wave-uniform
// base + lane*16; global src is per-lane. Retirement tracked by vmcnt.
typedef const __attribute__((address_space(1))) void g1cv;
typedef __attribute__((address_space(3))) void l3v;
__device__ __forceinline__ void gll16(const void* g, void* l) {
    __builtin_amdgcn_global_load_lds((g1cv*)g, (l3v*)l, 16, 0, 0);
}
#define WAITVM4 asm volatile("s_waitcnt vmcnt(4)" ::: "memory")
#define WAITVM0 asm volatile("s_waitcnt vmcnt(0)" ::: "memory")

// Write-through coherent 2B store pair (hi, lo). sc0 sc1 -> store goes to the
// device coherent point directly, never dirty in producer L2 -> barrier
// release needs only s_waitcnt vmcnt(0), no buffer_wbl2.
__device__ __forceinline__ void storeh_coh(bf16* ph, bf16* pl,
                                           unsigned short vh, unsigned short vl) {
    asm volatile(
        "global_store_short %0, %2, off sc0 sc1\n\t"
        "global_store_short %1, %3, off sc0 sc1"
        :: "v"(ph), "v"(pl), "v"(vh), "v"(vl)
        : "memory");
}

// Coherent 32KiB global->LDS stage (hi 16KiB + lo 16KiB), 512 threads.
__device__ __forceinline__ void stage32k_512(const bf16* gh, const bf16* gl,
                                             bf16* lds, int tid) {
    u32x4 a0, a1, b0, b1;
    const bf16* p0 = gh + tid * 8;
    const bf16* p1 = p0 + 4096;       // +8192 B
    const bf16* q0 = gl + tid * 8;
    const bf16* q1 = q0 + 4096;
    asm volatile(
        "global_load_dwordx4 %0, %4, off sc0 sc1\n\t"
        "global_load_dwordx4 %1, %5, off sc0 sc1\n\t"
        "global_load_dwordx4 %2, %6, off sc0 sc1\n\t"
        "global_load_dwordx4 %3, %7, off sc0 sc1\n\t"
        "s_waitcnt vmcnt(0)"
        : "=&v"(a0), "=&v"(a1), "=&v"(b0), "=&v"(b1)
        : "v"(p0), "v"(p1), "v"(q0), "v"(q1)
        : "memory");
    *(u32x4*)(lds + tid * 8)               = a0;   // hi plane [0, 8192)
    *(u32x4*)(lds + tid * 8 + 4096)        = a1;
    *(u32x4*)(lds + 8192 + tid * 8)        = b0;   // lo plane [8192, 16384)
    *(u32x4*)(lds + 8192 + tid * 8 + 4096) = b1;
}

// fp32x8 -> (bf16 hi, bf16 lo) x8.  lo = rnd(v - hi).
__device__ __forceinline__ void split_store8(const float* __restrict__ src,
                                             bf16* __restrict__ dh, bf16* __restrict__ dl) {
    float f[8];
    *(float4*)f       = *(const float4*)src;
    *(float4*)(f + 4) = *(const float4*)(src + 4);
    bf16x8 oh, ol;
    #pragma unroll
    for (int j = 0; j < 8; ++j) { bf16 h = (bf16)f[j]; oh[j] = h; ol[j] = (bf16)(f[j] - (float)h); }
    *(bf16x8*)dh = oh; *(bf16x8*)dl = ol;
}

// ---------------- software grid barrier (no wbl2, no cache invalidation) ----
__device__ __forceinline__ void gbarrier(unsigned* __restrict__ flags, int bid, unsigned epoch) {
    asm volatile("s_waitcnt vmcnt(0)" ::: "memory");   // release: coherent h stores done
    __syncthreads();
    if (threadIdx.x == 0)
        asm volatile("global_store_dword %0, %1, off sc0 sc1"
                     :: "v"(&flags[bid]), "v"(epoch) : "memory");
    if (threadIdx.x < 64) {
        const int l = threadIdx.x;
        for (;;) {
            unsigned f0 = __hip_atomic_load(&flags[l],       __ATOMIC_RELAXED, __HIP_MEMORY_SCOPE_AGENT);
            unsigned f1 = __hip_atomic_load(&flags[l + 64],  __ATOMIC_RELAXED, __HIP_MEMORY_SCOPE_AGENT);
            unsigned f2 = __hip_atomic_load(&flags[l + 128], __ATOMIC_RELAXED, __HIP_MEMORY_SCOPE_AGENT);
            unsigned f3 = __hip_atomic_load(&flags[l + 192], __ATOMIC_RELAXED, __HIP_MEMORY_SCOPE_AGENT);
            if (__all(f0 >= epoch && f1 >= epoch && f2 >= epoch && f3 >= epoch)) break;
            __builtin_amdgcn_s_sleep(1);
        }
    }
    __syncthreads();
}

// ---------------- precompute kernels (UNCHANGED packing) ----------------

__global__ void k_pack_wa(const float* __restrict__ wihL, const float* __restrict__ whhL,
                          const float* __restrict__ wihR, const float* __restrict__ whhR,
                          bf16* __restrict__ wah, bf16* __restrict__ wal) {
    int gid = blockIdx.x * 256 + threadIdx.x;      // 393,216
    int lane = gid & 63, u = gid >> 6;             // u < 6144
    int kb = u % 24; int tn = (u / 24) & 127; int dir = u / 3072;
    int r = lane & 15, q = lane >> 4;
    int n = tn * 16 + r, k = kb * 32 + q * 8;
    const float* wih = dir ? wihR : wihL;          // layer 0 slice at offset 0
    const float* whh = dir ? whhR : whhL;
    const float* src = (k < 256) ? (wih + (size_t)n * 256 + k)
                                 : (whh + (size_t)n * 512 + (k - 256));
    split_store8(src, wah + (size_t)u * UNITE + lane * 8, wal + (size_t)u * UNITE + lane * 8);
}

__global__ void k_wcomb(const float* __restrict__ wihL, const float* __restrict__ wfcL,
                        const float* __restrict__ wihR, const float* __restrict__ wfcR,
                        float* __restrict__ wcf) {
    size_t gid = (size_t)blockIdx.x * 256 + threadIdx.x;  // 2,097,152
    int k = gid & 511; int n = (gid >> 9) & 2047; int dir = (int)(gid >> 20);
    const float* wih1 = (dir ? wihR : wihL) + (size_t)2048 * 256;  // layer 1
    const float* wfc0 = (dir ? wfcR : wfcL);                        // layer 0
    float s = 0.f;
    #pragma unroll 8
    for (int v = 0; v < 256; ++v)
        s = fmaf(wih1[(size_t)n * 256 + v], wfc0[(size_t)v * 512 + k], s);
    wcf[gid] = s;
}

__global__ void k_pack_wb(const float* __restrict__ whhL, const float* __restrict__ whhR,
                          const float* __restrict__ wcf,
                          bf16* __restrict__ wbh, bf16* __restrict__ wbl) {
    int gid = blockIdx.x * 256 + threadIdx.x;      // 524,288
    int lane = gid & 63, u = gid >> 6;             // u < 8192
    int kb = u & 31, tn = (u >> 5) & 127, dir = u >> 12;
    int r = lane & 15, q = lane >> 4;
    int n = tn * 16 + r, k = kb * 32 + q * 8;
    const float* src;
    if (k < 512) {
        src = wcf + ((size_t)dir * 2048 + n) * 512 + k;
    } else {
        const float* whh1 = (dir ? whhR : whhL) + (size_t)2048 * 512;
        src = whh1 + (size_t)n * 512 + (k - 512);
    }
    split_store8(src, wbh + (size_t)u * UNITE + lane * 8, wbl + (size_t)u * UNITE + lane * 8);
}

__global__ void k_pack_wc(const float* __restrict__ wfcL, const float* __restrict__ wfcR,
                          bf16* __restrict__ wch, bf16* __restrict__ wcl) {
    int gid = blockIdx.x * 256 + threadIdx.x;      // 32,768
    int lane = gid & 63, u = gid >> 6;             // u < 512
    int kb = u & 15, tn = (u >> 4) & 15, dir = u >> 8;
    int r = lane & 15, q = lane >> 4;
    int n = tn * 16 + r, k = kb * 32 + q * 8;
    const float* wfc1 = (dir ? wfcR : wfcL) + (size_t)256 * 512;   // layer 1
    split_store8(wfc1 + (size_t)n * 512 + k,
                 wch + (size_t)u * UNITE + lane * 8, wcl + (size_t)u * UNITE + lane * 8);
}

__global__ void k_bias(const float* __restrict__ bihL, const float* __restrict__ bhhL,
                       const float* __restrict__ bfcL, const float* __restrict__ wihL,
                       const float* __restrict__ bihR, const float* __restrict__ bhhR,
                       const float* __restrict__ bfcR, const float* __restrict__ wihR,
                       float* __restrict__ ba, float* __restrict__ bb, float* __restrict__ bc) {
    int gid = blockIdx.x * 256 + threadIdx.x;      // 4096
    int n = gid & 2047, dir = gid >> 11;
    const float* bih = dir ? bihR : bihL;
    const float* bhh = dir ? bhhR : bhhL;
    const float* bfc = dir ? bfcR : bfcL;
    const float* wih1 = (dir ? wihR : wihL) + (size_t)2048 * 256;
    ba[dir * 2048 + n] = bih[n] + bhh[n];
    float s = bih[2048 + n] + bhh[2048 + n];
    #pragma unroll 8
    for (int v = 0; v < 256; ++v)
        s = fmaf(bfc[v], wih1[(size_t)n * 256 + v], s);
    bb[dir * 2048 + n] = s;
    if (n < 256) bc[dir * 256 + n] = bfc[256 + n];
}

// ---------------- main persistent kernel ----------------
// R7: weight reads converted to DOUBLE-BUFFERED ASYNC LDS STAGING via
// global_load_lds. R6 evidence: ~440 ns per weight load = 1 outstanding
// load/wave (compiler lockstep load->wait->MFMA, VGPR-starved) -> 4 GB/s/CU.
// Per wave per chunk: 4 gll (2 gate-groups x hi/lo = 4 KiB), issue chunk c+1,
// s_waitcnt vmcnt(4) (retires chunk c; vmcnt retires in issue order, any
// compiler-inserted vmem only makes the wait conservative), then ds_read +
// 6 MFMAs on chunk c. x loads hoisted into regs ahead of the pipeline.
// LDS: h0s 32K + h1s 32K + wbuf 64K + gred 16K + yred 2K = 146 KiB, 1 blk/CU.
__global__ __launch_bounds__(512, 2) void bilstm_main(
    const float* __restrict__ x,
    const bf16* __restrict__ wah, const bf16* __restrict__ wal,
    const bf16* __restrict__ wbh, const bf16* __restrict__ wbl,
    const bf16* __restrict__ wch, const bf16* __restrict__ wcl,
    bf16* __restrict__ h0pk, bf16* __restrict__ h1pk,
    const float* __restrict__ ba, const float* __restrict__ bb,
    const float* __restrict__ bc, float* __restrict__ out,
    unsigned* __restrict__ flags)
{
    const int bid  = blockIdx.x;
    const int nslc = bid & 7;            // == XCD (bid%8 heuristic)
    const int bq   = (bid >> 3) & 15;    // batch-row slice
    const int dir  = bid >> 7;
    const int tid  = threadIdx.x;
    const int wv   = tid >> 6;
    const int wq   = wv & 3;             // virtual wave
    const int kg   = wv >> 2;            // K-group
    const int lane = tid & 63;
    const int r = lane & 15, q = lane >> 4;

    __shared__ __align__(16) bf16 h0s[16384];          // 32 KiB
    __shared__ __align__(16) bf16 h1s[16384];          // 32 KiB
    __shared__ __align__(16) bf16 wbuf[2][8][4][512];  // 64 KiB: [buf][wave][unit][elem]
    __shared__ __align__(16) float gred[4][4][64][4];  // 16 KiB: [wq][g][lane][i]
    __shared__ __align__(16) float yred[2][64][4];     // 2 KiB

    const bf16* WAh = wah + (size_t)dir * WA_UNITS_DIR * UNITE;
    const bf16* WAl = wal + (size_t)dir * WA_UNITS_DIR * UNITE;
    const bf16* WBh = wbh + (size_t)dir * WB_UNITS_DIR * UNITE;
    const bf16* WBl = wbl + (size_t)dir * WB_UNITS_DIR * UNITE;
    const bf16* WCh = wch + (size_t)dir * WC_UNITS_DIR * UNITE;
    const bf16* WCl = wcl + (size_t)dir * WC_UNITS_DIR * UNITE;
    bf16* H0 = h0pk + (size_t)dir * 4 * HPAR;   // [parity][hi/lo][HPAR]
    bf16* H1 = h1pk + (size_t)dir * 4 * HPAR;
    const float* BA = ba + dir * 2048;
    const float* BB = bb + dir * 2048;
    const float* BC = bc + dir * 256;

    const int nbase = nslc * 4 + wq;             // n-unit (16 gate cols) per virtual wave
    const int col   = nslc * 64 + wq * 16 + r;   // hidden col this lane owns
    const float bia0 = BA[col], bia1 = BA[512 + col], bia2 = BA[1024 + col], bia3 = BA[1536 + col];
    const float bib0 = BB[col], bib1 = BB[512 + col], bib2 = BB[1024 + col], bib3 = BB[1536 + col];

    const int hunit  = bq * 16 + nslc * 2 + (wq >> 1);
    const int hw_off = ((wq & 1) * 2 + (r >> 3)) * 128 + q * 32 + (r & 7);

    const int tn  = nslc * 2 + (wq & 1);
    const float byc = BC[tn * 16 + r];

// issue one chunk: 4 gll into wbuf[c&1][wv][0..3] for gate-groups (gh, gh+1)
#define ISSUE_CHUNK(Wh, Wl, STRIDE, KB, C) do {                                          \
    const int gh_ = ((C) & 1) * 2;                                                       \
    const int bf_ = (C) & 1;                                                             \
    const size_t u0_ = ((size_t)((gh_ * 32 + nbase) * (STRIDE) + (KB))) * UNITE + (size_t)lane * 8; \
    const size_t u1_ = ((size_t)(((gh_ + 1) * 32 + nbase) * (STRIDE) + (KB))) * UNITE + (size_t)lane * 8; \
    gll16((const void*)((Wh) + u0_), (void*)&wbuf[bf_][wv][0][0]);                       \
    gll16((const void*)((Wl) + u0_), (void*)&wbuf[bf_][wv][1][0]);                       \
    gll16((const void*)((Wh) + u1_), (void*)&wbuf[bf_][wv][2][0]);                       \
    gll16((const void*)((Wl) + u1_), (void*)&wbuf[bf_][wv][3][0]);                       \
} while (0)

#define COMPUTE_CHUNK(AH, AL, C) do {                                                    \
    const int gh_ = ((C) & 1) * 2;                                                       \
    const int bf_ = (C) & 1;                                                             \
    bf16x8 bh0_ = *(const bf16x8*)&wbuf[bf_][wv][0][lane * 8];                           \
    bf16x8 bl0_ = *(const bf16x8*)&wbuf[bf_][wv][1][lane * 8];                           \
    bf16x8 bh1_ = *(const bf16x8*)&wbuf[bf_][wv][2][lane * 8];                           \
    bf16x8 bl1_ = *(const bf16x8*)&wbuf[bf_][wv][3][lane * 8];                           \
    MFMA(acc[gh_], (AH), bh0_); MFMA(acc[gh_], (AH), bl0_); MFMA(acc[gh_], (AL), bh0_);  \
    MFMA(acc[gh_ + 1], (AH), bh1_); MFMA(acc[gh_ + 1], (AH), bl1_); MFMA(acc[gh_ + 1], (AL), bh1_); \
} while (0)

    f32x4 c0 = {0.f, 0.f, 0.f, 0.f}, c1 = {0.f, 0.f, 0.f, 0.f};
    unsigned epoch = 0;

    // zero h0s (h0 at t=-1 is zero)
    #pragma unroll
    for (int k2 = 0; k2 < 4; ++k2) *(u32x4*)(h0s + tid * 8 + k2 * 4096) = (u32x4){0, 0, 0, 0};
    __syncthreads();

    for (int t = 0; t <= TSTEPS; ++t) {
        const int pw = t & 1, pr = pw ^ 1;
        // ---- S1: stage h1[pr] (ends vmcnt(0)); gates0 pipeline ----
        stage32k_512(H1 + (size_t)pr * 2 * HPAR + (size_t)bq * 8192,
                     H1 + (size_t)pr * 2 * HPAR + HPAR + (size_t)bq * 8192, h1s, tid);
        {
            f32x4 acc[4] = {{0,0,0,0},{0,0,0,0},{0,0,0,0},{0,0,0,0}};
            if (t < TSTEPS) {
                bf16x8 axh[8], axl[8];
                if (kg == 0) {           // hoist x loads + bf16-split conversion
                    const int pos = dir ? (255 - t) : t;
                    const float* xp = x + ((size_t)(bq * 16 + r) * 256 + pos) * 256 + q * 8;
                    #pragma unroll
                    for (int kb = 0; kb < 8; ++kb) {
                        float xf[8];
                        *(float4*)xf       = *(const float4*)(xp + kb * 32);
                        *(float4*)(xf + 4) = *(const float4*)(xp + kb * 32 + 4);
                        #pragma unroll
                        for (int j = 0; j < 8; ++j) {
                            bf16 h = (bf16)xf[j];
                            axh[kb][j] = h; axl[kb][j] = (bf16)(xf[j] - (float)h);
                        }
                    }
                }
                // pipeline over 24 chunks: kbidx = kg*12 + (c>>1)
                const int kbb = kg * 12;
                ISSUE_CHUNK(WAh, WAl, 24, kbb, 0);
                #pragma unroll
                for (int c = 0; c < 24; ++c) {
                    if (c + 1 < 24) { ISSUE_CHUNK(WAh, WAl, 24, kbb + ((c + 1) >> 1), c + 1); WAITVM4; }
                    else            { WAITVM0; }
                    const int idx = c >> 1;
                    bf16x8 ah, al;
                    if (kg == 0 && idx < 8) { ah = axh[idx]; al = axl[idx]; }
                    else {
                        const int hk = kbb + idx - 8;    // kg0: 0..3, kg1: 4..15
                        ah = *(const bf16x8*)(h0s + hk * 512 + lane * 8);
                        al = *(const bf16x8*)(h0s + 8192 + hk * 512 + lane * 8);
                    }
                    COMPUTE_CHUNK(ah, al, c);
                }
                if (kg == 1) {
                    #pragma unroll
                    for (int g = 0; g < 4; ++g) *(f32x4*)&gred[wq][g][lane][0] = acc[g];
                }
            }
            __syncthreads();   // SYNC1: h1s staged; gred visible
            // ---- S2: kg0 finish gates0; kg1 partial y ----
            if (t < TSTEPS && kg == 0) {
                bf16* WH = H0 + (size_t)pw * 2 * HPAR + (size_t)hunit * 512 + hw_off;
                bf16* WL = WH + HPAR;
                #pragma unroll
                for (int i = 0; i < 4; ++i) {
                    float gi = sigmoidf_(acc[0][i] + gred[wq][0][lane][i] + bia0);
                    float gf = sigmoidf_(acc[1][i] + gred[wq][1][lane][i] + bia1);
                    float gg = tanhf_   (acc[2][i] + gred[wq][2][lane][i] + bia2);
                    float go = sigmoidf_(acc[3][i] + gred[wq][3][lane][i] + bia3);
                    float cc = gf * c0[i] + gi * gg;
                    c0[i] = cc;
                    float hv = go * tanhf_(cc);
                    bf16 hh = (bf16)hv;
                    bf16 hl = (bf16)(hv - (float)hh);
                    storeh_coh(WH + i * 8, WL + i * 8,
                               __builtin_bit_cast(unsigned short, hh),
                               __builtin_bit_cast(unsigned short, hl));
                }
            }
        }
        f32x4 accy = {0, 0, 0, 0};
        if (t >= 1 && kg == 1) {
            const int kb0 = (wq >> 1) * 8;
            #pragma unroll
            for (int kk = 0; kk < 8; ++kk) {
                const int kb = kb0 + kk;
                bf16x8 ah = *(const bf16x8*)(h1s + kb * 512 + lane * 8);
                bf16x8 al = *(const bf16x8*)(h1s + 8192 + kb * 512 + lane * 8);
                const size_t wu = ((size_t)(tn * 16 + kb)) * UNITE + lane * 8;
                bf16x8 bh = *(const bf16x8*)(WCh + wu);
                bf16x8 bl = *(const bf16x8*)(WCl + wu);
                f32x4 t0 = accy;
                MFMA(t0, ah, bh); MFMA(t0, ah, bl); MFMA(t0, al, bh);
                accy = t0;
            }
            if (wq >= 2) *(f32x4*)&yred[wq & 1][lane][0] = accy;
        }
        __syncthreads();   // SYNC2: yred visible
        if (t >= 1 && kg == 1 && wq < 2) {
            const int tout = dir ? (255 + (t - 1)) : (t - 1);
            #pragma unroll
            for (int i = 0; i < 4; ++i)
                out[((size_t)(bq * 16 + 4 * q + i) * 510 + tout) * 256 + tn * 16 + r]
                    = accy[i] + yred[wq][lane][i] + byc;
        }
        ++epoch; gbarrier(flags, bid, epoch);
        // ---- phase B ----
        if (t < TSTEPS) {
            stage32k_512(H0 + (size_t)pw * 2 * HPAR + (size_t)bq * 8192,
                         H0 + (size_t)pw * 2 * HPAR + HPAR + (size_t)bq * 8192, h0s, tid);
            __syncthreads();   // SYNC3: h0s ready (persists into next step's phase A)
            f32x4 acc[4] = {{0,0,0,0},{0,0,0,0},{0,0,0,0},{0,0,0,0}};
            const int kbb = kg * 16;
            ISSUE_CHUNK(WBh, WBl, 32, kbb, 0);
            #pragma unroll
            for (int c = 0; c < 32; ++c) {
                if (c + 1 < 32) { ISSUE_CHUNK(WBh, WBl, 32, kbb + ((c + 1) >> 1), c + 1); WAITVM4; }
                else            { WAITVM0; }
                const int idx = c >> 1;
                const bf16* hs = (kg == 0) ? h0s : h1s;
                bf16x8 ah = *(const bf16x8*)(hs + idx * 512 + lane * 8);
                bf16x8 al = *(const bf16x8*)(hs + 8192 + idx * 512 + lane * 8);
                COMPUTE_CHUNK(ah, al, c);
            }
            if (kg == 1) {
                #pragma unroll
                for (int g = 0; g < 4; ++g) *(f32x4*)&gred[wq][g][lane][0] = acc[g];
            }
            __syncthreads();   // SYNC4: gred visible
            if (kg == 0) {
                bf16* WH = H1 + (size_t)pw * 2 * HPAR + (size_t)hunit * 512 + hw_off;
                bf16* WL = WH + HPAR;
                #pragma unroll
                for (int i = 0; i < 4; ++i) {
                    float gi = sigmoidf_(acc[0][i] + gred[wq][0][lane][i] + bib0);
                    float gf = sigmoidf_(acc[1][i] + gred[wq][1][lane][i] + bib1);
                    float gg = tanhf_   (acc[2][i] + gred[wq][2][lane][i] + bib2);
                    float go = sigmoidf_(acc[3][i] + gred[wq][3][lane][i] + bib3);
                    float cc = gf * c1[i] + gi * gg;
                    c1[i] = cc;
                    float hv = go * tanhf_(cc);
                    bf16 hh = (bf16)hv;
                    bf16 hl = (bf16)(hv - (float)hh);
                    storeh_coh(WH + i * 8, WL + i * 8,
                               __builtin_bit_cast(unsigned short, hh),
                               __builtin_bit_cast(unsigned short, hl));
                }
            }
        }
        ++epoch; gbarrier(flags, bid, epoch);
    }
#undef ISSUE_CHUNK
#undef COMPUTE_CHUNK
}

// ---------------- host launch ----------------
extern "C" void kernel_launch(void* const* d_in, const int* in_sizes, int n_in,
                              void* d_out, int out_size, void* d_ws, size_t ws_size,
                              hipStream_t stream) {
    (void)in_sizes; (void)n_in; (void)ws_size;
    const float* x    = (const float*)d_in[0];
    const float* wihL = (const float*)d_in[1];
    const float* whhL = (const float*)d_in[2];
    const float* bihL = (const float*)d_in[3];
    const float* bhhL = (const float*)d_in[4];
    const float* wfcL = (const float*)d_in[5];
    const float* bfcL = (const float*)d_in[6];
    const float* wihR = (const float*)d_in[7];
    const float* whhR = (const float*)d_in[8];
    const float* bihR = (const float*)d_in[9];
    const float* bhhR = (const float*)d_in[10];
    const float* wfcR = (const float*)d_in[11];
    const float* bfcR = (const float*)d_in[12];

    char* ws = (char*)d_ws;
    size_t off = 0;
    auto take = [&](size_t bytes) -> char* {
        off = (off + 255) & ~(size_t)255;
        char* p = ws + off;
        off += bytes;
        return p;
    };
    bf16*     WAH = (bf16*)take((size_t)2 * WA_UNITS_DIR * 1024);  // 6 MiB
    bf16*     WAL = (bf16*)take((size_t)2 * WA_UNITS_DIR * 1024);  // 6 MiB
    bf16*     WBH = (bf16*)take((size_t)2 * WB_UNITS_DIR * 1024);  // 8 MiB
    bf16*     WBL = (bf16*)take((size_t)2 * WB_UNITS_DIR * 1024);  // 8 MiB
    bf16*     WCH = (bf16*)take((size_t)2 * WC_UNITS_DIR * 1024);  // 0.5 MiB
    bf16*     WCL = (bf16*)take((size_t)2 * WC_UNITS_DIR * 1024);  // 0.5 MiB
    bf16*     H0  = (bf16*)take((size_t)8 * HPAR * 2);             // 2 MiB (dir x parity x hi/lo)
    bf16*     H1  = (bf16*)take((size_t)8 * HPAR * 2);             // 2 MiB
    float*    WCF = (float*)take((size_t)2 * 2048 * 512 * 4);      // 8 MiB fp32 scratch
    float*    BA  = (float*)take((size_t)2 * 2048 * 4);
    float*    BB  = (float*)take((size_t)2 * 2048 * 4);
    float*    BC  = (float*)take((size_t)2 * 256 * 4);
    unsigned* FLG = (unsigned*)take((size_t)256 * 4);              // barrier flags

    hipMemsetAsync(H0, 0, (size_t)8 * HPAR * 2, stream);
    hipMemsetAsync(H1, 0, (size_t)8 * HPAR * 2, stream);
    hipMemsetAsync(FLG, 0, (size_t)256 * 4, stream);               // clear 0xAA poison!
    hipMemsetAsync(d_out, 0, (size_t)out_size * 4, stream);

    k_pack_wa<<<1536, 256, 0, stream>>>(wihL, whhL, wihR, whhR, WAH, WAL);
    k_wcomb  <<<8192, 256, 0, stream>>>(wihL, wfcL, wihR, wfcR, WCF);
    k_pack_wb<<<2048, 256, 0, stream>>>(whhL, whhR, WCF, WBH, WBL);
    k_pack_wc<<<128,  256, 0, stream>>>(wfcL, wfcR, WCH, WCL);
    k_bias   <<<16,   256, 0, stream>>>(bihL, bhhL, bfcL, wihL, bihR, bhhR, bfcR, wihR, BA, BB, BC);

    bilstm_main<<<256, 512, 0, stream>>>(x, WAH, WAL, WBH, WBL, WCH, WCL,
                                         H0, H1, BA, BB, BC, (float*)d_out, FLG);
}

// Round 10
// 27222.839 us; speedup vs baseline: 1.0693x; 1.0693x over previous
//
#include <hip/hip_runtime.h>
#include <hip/hip_bf16.h>

using bf16   = __bf16;
using bf16x8 = __attribute__((ext_vector_type(8))) __bf16;
using f32x4  = __attribute__((ext_vector_type(4))) float;
using u32x4  = __attribute__((ext_vector_type(4))) unsigned int;

#define TSTEPS 255
// element (bf16) counts
#define UNITE  512              // elements per 1KiB MFMA fragment unit
#define HPAR   (16*16*512)      // one (parity,hi-or-lo) h plane: 16 bq x 16 kb units
#define WA_UNITS_DIR (128*24)
#define WB_UNITS_DIR (128*32)
#define WC_UNITS_DIR (16*16)

#define MFMA(acc, a, b) acc = __builtin_amdgcn_mfma_f32_16x16x32_bf16((a), (b), (acc), 0, 0, 0)

__device__ __forceinline__ float sigmoidf_(float x) { return 1.f / (1.f + __expf(-x)); }
__device__ __forceinline__ float tanhf_(float x) {
    float e = __expf(-2.f * fabsf(x));
    float t = (1.f - e) / (1.f + e);
    return copysignf(t, x);
}

// async global->LDS 16B/lane (1 KiB/wave per call). LDS dest is wave-uniform
// base + lane*16; global src is per-lane. Retirement tracked by vmcnt.
typedef const __attribute__((address_space(1))) void g1cv;
typedef __attribute__((address_space(3))) void l3v;
__device__ __forceinline__ void gll16(const void* g, void* l) {
    __builtin_amdgcn_global_load_lds((g1cv*)g, (l3v*)l, 16, 0, 0);
}
#define WAITVM4 asm volatile("s_waitcnt vmcnt(4)" ::: "memory")
#define WAITVM0 asm volatile("s_waitcnt vmcnt(0)" ::: "memory")

// Write-through coherent 2B store pair (hi, lo). sc0 sc1 -> store goes to the
// device coherent point directly, never dirty in producer L2 -> barrier
// release needs only s_waitcnt vmcnt(0), no buffer_wbl2. No L2 allocation.
__device__ __forceinline__ void storeh_coh(bf16* ph, bf16* pl,
                                           unsigned short vh, unsigned short vl) {
    asm volatile(
        "global_store_short %0, %2, off sc0 sc1\n\t"
        "global_store_short %1, %3, off sc0 sc1"
        :: "v"(ph), "v"(pl), "v"(vh), "v"(vl)
        : "memory");
}

// out stores bypass L2 (no write-allocate pollution of the weight set).
// Same single-instruction pattern as the proven barrier flag store.
__device__ __forceinline__ void storeout_coh(float* p, float v) {
    asm volatile("global_store_dword %0, %1, off sc0 sc1" :: "v"(p), "v"(v) : "memory");
}

// Coherent 32KiB global->LDS stage (hi 16KiB + lo 16KiB), 512 threads.
__device__ __forceinline__ void stage32k_512(const bf16* gh, const bf16* gl,
                                             bf16* lds, int tid) {
    u32x4 a0, a1, b0, b1;
    const bf16* p0 = gh + tid * 8;
    const bf16* p1 = p0 + 4096;       // +8192 B
    const bf16* q0 = gl + tid * 8;
    const bf16* q1 = q0 + 4096;
    asm volatile(
        "global_load_dwordx4 %0, %4, off sc0 sc1\n\t"
        "global_load_dwordx4 %1, %5, off sc0 sc1\n\t"
        "global_load_dwordx4 %2, %6, off sc0 sc1\n\t"
        "global_load_dwordx4 %3, %7, off sc0 sc1\n\t"
        "s_waitcnt vmcnt(0)"
        : "=&v"(a0), "=&v"(a1), "=&v"(b0), "=&v"(b1)
        : "v"(p0), "v"(p1), "v"(q0), "v"(q1)
        : "memory");
    *(u32x4*)(lds + tid * 8)               = a0;   // hi plane [0, 8192)
    *(u32x4*)(lds + tid * 8 + 4096)        = a1;
    *(u32x4*)(lds + 8192 + tid * 8)        = b0;   // lo plane [8192, 16384)
    *(u32x4*)(lds + 8192 + tid * 8 + 4096) = b1;
}

// fp32x8 -> (bf16 hi, bf16 lo) x8.  lo = rnd(v - hi).
__device__ __forceinline__ void split_store8(const float* __restrict__ src,
                                             bf16* __restrict__ dh, bf16* __restrict__ dl) {
    float f[8];
    *(float4*)f       = *(const float4*)src;
    *(float4*)(f + 4) = *(const float4*)(src + 4);
    bf16x8 oh, ol;
    #pragma unroll
    for (int j = 0; j < 8; ++j) { bf16 h = (bf16)f[j]; oh[j] = h; ol[j] = (bf16)(f[j] - (float)h); }
    *(bf16x8*)dh = oh; *(bf16x8*)dl = ol;
}

// ---------------- software grid barrier (no wbl2, no cache invalidation) ----
__device__ __forceinline__ void gbarrier(unsigned* __restrict__ flags, int bid, unsigned epoch) {
    asm volatile("s_waitcnt vmcnt(0)" ::: "memory");   // release: coherent h stores done
    __syncthreads();
    if (threadIdx.x == 0)
        asm volatile("global_store_dword %0, %1, off sc0 sc1"
                     :: "v"(&flags[bid]), "v"(epoch) : "memory");
    if (threadIdx.x < 64) {
        const int l = threadIdx.x;
        for (;;) {
            unsigned f0 = __hip_atomic_load(&flags[l],       __ATOMIC_RELAXED, __HIP_MEMORY_SCOPE_AGENT);
            unsigned f1 = __hip_atomic_load(&flags[l + 64],  __ATOMIC_RELAXED, __HIP_MEMORY_SCOPE_AGENT);
            unsigned f2 = __hip_atomic_load(&flags[l + 128], __ATOMIC_RELAXED, __HIP_MEMORY_SCOPE_AGENT);
            unsigned f3 = __hip_atomic_load(&flags[l + 192], __ATOMIC_RELAXED, __HIP_MEMORY_SCOPE_AGENT);
            if (__all(f0 >= epoch && f1 >= epoch && f2 >= epoch && f3 >= epoch)) break;
            __builtin_amdgcn_s_sleep(1);
        }
    }
    __syncthreads();
}

// ---------------- precompute kernels (UNCHANGED packing) ----------------

__global__ void k_pack_wa(const float* __restrict__ wihL, const float* __restrict__ whhL,
                          const float* __restrict__ wihR, const float* __restrict__ whhR,
                          bf16* __restrict__ wah, bf16* __restrict__ wal) {
    int gid = blockIdx.x * 256 + threadIdx.x;      // 393,216
    int lane = gid & 63, u = gid >> 6;             // u < 6144
    int kb = u % 24; int tn = (u / 24) & 127; int dir = u / 3072;
    int r = lane & 15, q = lane >> 4;
    int n = tn * 16 + r, k = kb * 32 + q * 8;
    const float* wih = dir ? wihR : wihL;          // layer 0 slice at offset 0
    const float* whh = dir ? whhR : whhL;
    const float* src = (k < 256) ? (wih + (size_t)n * 256 + k)
                                 : (whh + (size_t)n * 512 + (k - 256));
    split_store8(src, wah + (size_t)u * UNITE + lane * 8, wal + (size_t)u * UNITE + lane * 8);
}

__global__ void k_wcomb(const float* __restrict__ wihL, const float* __restrict__ wfcL,
                        const float* __restrict__ wihR, const float* __restrict__ wfcR,
                        float* __restrict__ wcf) {
    size_t gid = (size_t)blockIdx.x * 256 + threadIdx.x;  // 2,097,152
    int k = gid & 511; int n = (gid >> 9) & 2047; int dir = (int)(gid >> 20);
    const float* wih1 = (dir ? wihR : wihL) + (size_t)2048 * 256;  // layer 1
    const float* wfc0 = (dir ? wfcR : wfcL);                        // layer 0
    float s = 0.f;
    #pragma unroll 8
    for (int v = 0; v < 256; ++v)
        s = fmaf(wih1[(size_t)n * 256 + v], wfc0[(size_t)v * 512 + k], s);
    wcf[gid] = s;
}

__global__ void k_pack_wb(const float* __restrict__ whhL, const float* __restrict__ whhR,
                          const float* __restrict__ wcf,
                          bf16* __restrict__ wbh, bf16* __restrict__ wbl) {
    int gid = blockIdx.x * 256 + threadIdx.x;      // 524,288
    int lane = gid & 63, u = gid >> 6;             // u < 8192
    int kb = u & 31, tn = (u >> 5) & 127, dir = u >> 12;
    int r = lane & 15, q = lane >> 4;
    int n = tn * 16 + r, k = kb * 32 + q * 8;
    const float* src;
    if (k < 512) {
        src = wcf + ((size_t)dir * 2048 + n) * 512 + k;
    } else {
        const float* whh1 = (dir ? whhR : whhL) + (size_t)2048 * 512;
        src = whh1 + (size_t)n * 512 + (k - 512);
    }
    split_store8(src, wbh + (size_t)u * UNITE + lane * 8, wbl + (size_t)u * UNITE + lane * 8);
}

__global__ void k_pack_wc(const float* __restrict__ wfcL, const float* __restrict__ wfcR,
                          bf16* __restrict__ wch, bf16* __restrict__ wcl) {
    int gid = blockIdx.x * 256 + threadIdx.x;      // 32,768
    int lane = gid & 63, u = gid >> 6;             // u < 512
    int kb = u & 15, tn = (u >> 4) & 15, dir = u >> 8;
    int r = lane & 15, q = lane >> 4;
    int n = tn * 16 + r, k = kb * 32 + q * 8;
    const float* wfc1 = (dir ? wfcR : wfcL) + (size_t)256 * 512;   // layer 1
    split_store8(wfc1 + (size_t)n * 512 + k,
                 wch + (size_t)u * UNITE + lane * 8, wcl + (size_t)u * UNITE + lane * 8);
}

__global__ void k_bias(const float* __restrict__ bihL, const float* __restrict__ bhhL,
                       const float* __restrict__ bfcL, const float* __restrict__ wihL,
                       const float* __restrict__ bihR, const float* __restrict__ bhhR,
                       const float* __restrict__ bfcR, const float* __restrict__ wihR,
                       float* __restrict__ ba, float* __restrict__ bb, float* __restrict__ bc) {
    int gid = blockIdx.x * 256 + threadIdx.x;      // 4096
    int n = gid & 2047, dir = gid >> 11;
    const float* bih = dir ? bihR : bihL;
    const float* bhh = dir ? bhhR : bhhL;
    const float* bfc = dir ? bfcR : bfcL;
    const float* wih1 = (dir ? wihR : wihL) + (size_t)2048 * 256;
    ba[dir * 2048 + n] = bih[n] + bhh[n];
    float s = bih[2048 + n] + bhh[2048 + n];
    #pragma unroll 8
    for (int v = 0; v < 256; ++v)
        s = fmaf(bfc[v], wih1[(size_t)n * 256 + v], s);
    bb[dir * 2048 + n] = s;
    if (n < 256) bc[dir * 256 + n] = bfc[256 + n];
}

// ---------------- main persistent kernel ----------------
// R9 (resubmit; R9 bench was an infra timeout): RUNTIME XCD-AWARE ROLE
// ASSIGNMENT. Evidence: ~50 MB/phase weight refetch despite each XCD's slice
// being only 2 MiB -> the bid%8->XCD heuristic is likely wrong (chunked
// dispatch makes every XCD demand all 16 MiB in a 4 MiB L2 = permanent
// thrash, matching FETCH). Fix: each block reads its REAL XCD via
// s_getreg(HW_REG_XCC_ID) [HW-verified MI355X], claims a slot via per-XCD
// atomic counter: nslc = actual XCD, (dir,bq) = slot. Pigeonhole: 146 KiB
// LDS -> 1 block/CU -> exactly 32 co-resident blocks per XCD. Barrier stays
// keyed by physical bid. Out stores sc0 sc1; x loads plain cached (R7 form).
__global__ __launch_bounds__(512, 2) void bilstm_main(
    const float* __restrict__ x,
    const bf16* __restrict__ wah, const bf16* __restrict__ wal,
    const bf16* __restrict__ wbh, const bf16* __restrict__ wbl,
    const bf16* __restrict__ wch, const bf16* __restrict__ wcl,
    bf16* __restrict__ h0pk, bf16* __restrict__ h1pk,
    const float* __restrict__ ba, const float* __restrict__ bb,
    const float* __restrict__ bc, float* __restrict__ out,
    unsigned* __restrict__ flags)
{
    const int bid  = blockIdx.x;
    const int tid  = threadIdx.x;
    const int wv   = tid >> 6;
    const int wq   = wv & 3;             // virtual wave
    const int kg   = wv >> 2;            // K-group
    const int lane = tid & 63;
    const int r = lane & 15, q = lane >> 4;

    __shared__ __align__(16) bf16 h0s[16384];          // 32 KiB
    __shared__ __align__(16) bf16 h1s[16384];          // 32 KiB
    __shared__ __align__(16) bf16 wbuf[2][8][4][512];  // 64 KiB: [buf][wave][unit][elem]
    __shared__ __align__(16) float gred[4][4][64][4];  // 16 KiB: [wq][g][lane][i]
    __shared__ __align__(16) float yred[2][64][4];     // 2 KiB
    __shared__ unsigned role_s;

    // ---- runtime role assignment: nslc = REAL XCD, (dir,bq) = atomic slot --
    if (tid == 0) {
        unsigned xcc;
        asm volatile("s_getreg_b32 %0, hwreg(HW_REG_XCC_ID, 0, 32)" : "=s"(xcc));
        xcc &= 7u;
        unsigned slot = __hip_atomic_fetch_add(&flags[256 + xcc], 1u,
                                               __ATOMIC_RELAXED, __HIP_MEMORY_SCOPE_AGENT);
        role_s = xcc * 32u + (slot & 31u);
    }
    __syncthreads();
    const unsigned role = role_s;
    const int nslc = role >> 5;          // == actual XCD
    const int bq   = role & 15;          // batch-row slice
    const int dir  = (role >> 4) & 1;

    const bf16* WAh = wah + (size_t)dir * WA_UNITS_DIR * UNITE;
    const bf16* WAl = wal + (size_t)dir * WA_UNITS_DIR * UNITE;
    const bf16* WBh = wbh + (size_t)dir * WB_UNITS_DIR * UNITE;
    const bf16* WBl = wbl + (size_t)dir * WB_UNITS_DIR * UNITE;
    const bf16* WCh = wch + (size_t)dir * WC_UNITS_DIR * UNITE;
    const bf16* WCl = wcl + (size_t)dir * WC_UNITS_DIR * UNITE;
    bf16* H0 = h0pk + (size_t)dir * 4 * HPAR;   // [parity][hi/lo][HPAR]
    bf16* H1 = h1pk + (size_t)dir * 4 * HPAR;
    const float* BA = ba + dir * 2048;
    const float* BB = bb + dir * 2048;
    const float* BC = bc + dir * 256;

    const int nbase = nslc * 4 + wq;             // n-unit (16 gate cols) per virtual wave
    const int col   = nslc * 64 + wq * 16 + r;   // hidden col this lane owns
    const float bia0 = BA[col], bia1 = BA[512 + col], bia2 = BA[1024 + col], bia3 = BA[1536 + col];
    const float bib0 = BB[col], bib1 = BB[512 + col], bib2 = BB[1024 + col], bib3 = BB[1536 + col];

    const int hunit  = bq * 16 + nslc * 2 + (wq >> 1);
    const int hw_off = ((wq & 1) * 2 + (r >> 3)) * 128 + q * 32 + (r & 7);

    const int tn  = nslc * 2 + (wq & 1);
    const float byc = BC[tn * 16 + r];

// issue one chunk: 4 gll into wbuf[c&1][wv][0..3] for gate-groups (gh, gh+1)
#define ISSUE_CHUNK(Wh, Wl, STRIDE, KB, C) do {                                          \
    const int gh_ = ((C) & 1) * 2;                                                       \
    const int bf_ = (C) & 1;                                                             \
    const size_t u0_ = ((size_t)((gh_ * 32 + nbase) * (STRIDE) + (KB))) * UNITE + (size_t)lane * 8; \
    const size_t u1_ = ((size_t)(((gh_ + 1) * 32 + nbase) * (STRIDE) + (KB))) * UNITE + (size_t)lane * 8; \
    gll16((const void*)((Wh) + u0_), (void*)&wbuf[bf_][wv][0][0]);                       \
    gll16((const void*)((Wl) + u0_), (void*)&wbuf[bf_][wv][1][0]);                       \
    gll16((const void*)((Wh) + u1_), (void*)&wbuf[bf_][wv][2][0]);                       \
    gll16((const void*)((Wl) + u1_), (void*)&wbuf[bf_][wv][3][0]);                       \
} while (0)

#define COMPUTE_CHUNK(AH, AL, C) do {                                                    \
    const int gh_ = ((C) & 1) * 2;                                                       \
    const int bf_ = (C) & 1;                                                             \
    bf16x8 bh0_ = *(const bf16x8*)&wbuf[bf_][wv][0][lane * 8];                           \
    bf16x8 bl0_ = *(const bf16x8*)&wbuf[bf_][wv][1][lane * 8];                           \
    bf16x8 bh1_ = *(const bf16x8*)&wbuf[bf_][wv][2][lane * 8];                           \
    bf16x8 bl1_ = *(const bf16x8*)&wbuf[bf_][wv][3][lane * 8];                           \
    MFMA(acc[gh_], (AH), bh0_); MFMA(acc[gh_], (AH), bl0_); MFMA(acc[gh_], (AL), bh0_);  \
    MFMA(acc[gh_ + 1], (AH), bh1_); MFMA(acc[gh_ + 1], (AH), bl1_); MFMA(acc[gh_ + 1], (AL), bh1_); \
} while (0)

    f32x4 c0 = {0.f, 0.f, 0.f, 0.f}, c1 = {0.f, 0.f, 0.f, 0.f};
    unsigned epoch = 0;

    // zero h0s (h0 at t=-1 is zero)
    #pragma unroll
    for (int k2 = 0; k2 < 4; ++k2) *(u32x4*)(h0s + tid * 8 + k2 * 4096) = (u32x4){0, 0, 0, 0};
    __syncthreads();

    for (int t = 0; t <= TSTEPS; ++t) {
        const int pw = t & 1, pr = pw ^ 1;
        // ---- S1: stage h1[pr] (ends vmcnt(0)); gates0 pipeline ----
        stage32k_512(H1 + (size_t)pr * 2 * HPAR + (size_t)bq * 8192,
                     H1 + (size_t)pr * 2 * HPAR + HPAR + (size_t)bq * 8192, h1s, tid);
        {
            f32x4 acc[4] = {{0,0,0,0},{0,0,0,0},{0,0,0,0},{0,0,0,0}};
            if (t < TSTEPS) {
                bf16x8 axh[8], axl[8];
                if (kg == 0) {           // hoist x loads + bf16-split conversion
                    const int pos = dir ? (255 - t) : t;
                    const float* xp = x + ((size_t)(bq * 16 + r) * 256 + pos) * 256 + q * 8;
                    #pragma unroll
                    for (int kb = 0; kb < 8; ++kb) {
                        float xf[8];
                        *(float4*)xf       = *(const float4*)(xp + kb * 32);
                        *(float4*)(xf + 4) = *(const float4*)(xp + kb * 32 + 4);
                        #pragma unroll
                        for (int j = 0; j < 8; ++j) {
                            bf16 h = (bf16)xf[j];
                            axh[kb][j] = h; axl[kb][j] = (bf16)(xf[j] - (float)h);
                        }
                    }
                }
                // pipeline over 24 chunks: kbidx = kg*12 + (c>>1)
                const int kbb = kg * 12;
                ISSUE_CHUNK(WAh, WAl, 24, kbb, 0);
                #pragma unroll
                for (int c = 0; c < 24; ++c) {
                    if (c + 1 < 24) { ISSUE_CHUNK(WAh, WAl, 24, kbb + ((c + 1) >> 1), c + 1); WAITVM4; }
                    else            { WAITVM0; }
                    const int idx = c >> 1;
                    bf16x8 ah, al;
                    if (kg == 0 && idx < 8) { ah = axh[idx]; al = axl[idx]; }
                    else {
                        const int hk = kbb + idx - 8;    // kg0: 0..3, kg1: 4..15
                        ah = *(const bf16x8*)(h0s + hk * 512 + lane * 8);
                        al = *(const bf16x8*)(h0s + 8192 + hk * 512 + lane * 8);
                    }
                    COMPUTE_CHUNK(ah, al, c);
                }
                if (kg == 1) {
                    #pragma unroll
                    for (int g = 0; g < 4; ++g) *(f32x4*)&gred[wq][g][lane][0] = acc[g];
                }
            }
            __syncthreads();   // SYNC1: h1s staged; gred visible
            // ---- S2: kg0 finish gates0; kg1 partial y ----
            if (t < TSTEPS && kg == 0) {
                bf16* WH = H0 + (size_t)pw * 2 * HPAR + (size_t)hunit * 512 + hw_off;
                bf16* WL = WH + HPAR;
                #pragma unroll
                for (int i = 0; i < 4; ++i) {
                    float gi = sigmoidf_(acc[0][i] + gred[wq][0][lane][i] + bia0);
                    float gf = sigmoidf_(acc[1][i] + gred[wq][1][lane][i] + bia1);
                    float gg = tanhf_   (acc[2][i] + gred[wq][2][lane][i] + bia2);
                    float go = sigmoidf_(acc[3][i] + gred[wq][3][lane][i] + bia3);
                    float cc = gf * c0[i] + gi * gg;
                    c0[i] = cc;
                    float hv = go * tanhf_(cc);
                    bf16 hh = (bf16)hv;
                    bf16 hl = (bf16)(hv - (float)hh);
                    storeh_coh(WH + i * 8, WL + i * 8,
                               __builtin_bit_cast(unsigned short, hh),
                               __builtin_bit_cast(unsigned short, hl));
                }
            }
        }
        f32x4 accy = {0, 0, 0, 0};
        if (t >= 1 && kg == 1) {
            const int kb0 = (wq >> 1) * 8;
            #pragma unroll
            for (int kk = 0; kk < 8; ++kk) {
                const int kb = kb0 + kk;
                bf16x8 ah = *(const bf16x8*)(h1s + kb * 512 + lane * 8);
                bf16x8 al = *(const bf16x8*)(h1s + 8192 + kb * 512 + lane * 8);
                const size_t wu = ((size_t)(tn * 16 + kb)) * UNITE + lane * 8;
                bf16x8 bh = *(const bf16x8*)(WCh + wu);
                bf16x8 bl = *(const bf16x8*)(WCl + wu);
                f32x4 t0 = accy;
                MFMA(t0, ah, bh); MFMA(t0, ah, bl); MFMA(t0, al, bh);
                accy = t0;
            }
            if (wq >= 2) *(f32x4*)&yred[wq & 1][lane][0] = accy;
        }
        __syncthreads();   // SYNC2: yred visible
        if (t >= 1 && kg == 1 && wq < 2) {
            const int tout = dir ? (255 + (t - 1)) : (t - 1);
            #pragma unroll
            for (int i = 0; i < 4; ++i)
                storeout_coh(out + ((size_t)(bq * 16 + 4 * q + i) * 510 + tout) * 256 + tn * 16 + r,
                             accy[i] + yred[wq][lane][i] + byc);
        }
        ++epoch; gbarrier(flags, bid, epoch);
        // ---- phase B ----
        if (t < TSTEPS) {
            stage32k_512(H0 + (size_t)pw * 2 * HPAR + (size_t)bq * 8192,
                         H0 + (size_t)pw * 2 * HPAR + HPAR + (size_t)bq * 8192, h0s, tid);
            __syncthreads();   // SYNC3: h0s ready (persists into next step's phase A)
            f32x4 acc[4] = {{0,0,0,0},{0,0,0,0},{0,0,0,0},{0,0,0,0}};
            const int kbb = kg * 16;
            ISSUE_CHUNK(WBh, WBl, 32, kbb, 0);
            #pragma unroll
            for (int c = 0; c < 32; ++c) {
                if (c + 1 < 32) { ISSUE_CHUNK(WBh, WBl, 32, kbb + ((c + 1) >> 1), c + 1); WAITVM4; }
                else            { WAITVM0; }
                const int idx = c >> 1;
                const bf16* hs = (kg == 0) ? h0s : h1s;
                bf16x8 ah = *(const bf16x8*)(hs + idx * 512 + lane * 8);
                bf16x8 al = *(const bf16x8*)(hs + 8192 + idx * 512 + lane * 8);
                COMPUTE_CHUNK(ah, al, c);
            }
            if (kg == 1) {
                #pragma unroll
                for (int g = 0; g < 4; ++g) *(f32x4*)&gred[wq][g][lane][0] = acc[g];
            }
            __syncthreads();   // SYNC4: gred visible
            if (kg == 0) {
                bf16* WH = H1 + (size_t)pw * 2 * HPAR + (size_t)hunit * 512 + hw_off;
                bf16* WL = WH + HPAR;
                #pragma unroll
                for (int i = 0; i < 4; ++i) {
                    float gi = sigmoidf_(acc[0][i] + gred[wq][0][lane][i] + bib0);
                    float gf = sigmoidf_(acc[1][i] + gred[wq][1][lane][i] + bib1);
                    float gg = tanhf_   (acc[2][i] + gred[wq][2][lane][i] + bib2);
                    float go = sigmoidf_(acc[3][i] + gred[wq][3][lane][i] + bib3);
                    float cc = gf * c1[i] + gi * gg;
                    c1[i] = cc;
                    float hv = go * tanhf_(cc);
                    bf16 hh = (bf16)hv;
                    bf16 hl = (bf16)(hv - (float)hh);
                    storeh_coh(WH + i * 8, WL + i * 8,
                               __builtin_bit_cast(unsigned short, hh),
                               __builtin_bit_cast(unsigned short, hl));
                }
            }
        }
        ++epoch; gbarrier(flags, bid, epoch);
    }
#undef ISSUE_CHUNK
#undef COMPUTE_CHUNK
}

// ---------------- host launch ----------------
extern "C" void kernel_launch(void* const* d_in, const int* in_sizes, int n_in,
                              void* d_out, int out_size, void* d_ws, size_t ws_size,
                              hipStream_t stream) {
    (void)in_sizes; (void)n_in; (void)ws_size;
    const float* x    = (const float*)d_in[0];
    const float* wihL = (const float*)d_in[1];
    const float* whhL = (const float*)d_in[2];
    const float* bihL = (const float*)d_in[3];
    const float* bhhL = (const float*)d_in[4];
    const float* wfcL = (const float*)d_in[5];
    const float* bfcL = (const float*)d_in[6];
    const float* wihR = (const float*)d_in[7];
    const float* whhR = (const float*)d_in[8];
    const float* bihR = (const float*)d_in[9];
    const float* bhhR = (const float*)d_in[10];
    const float* wfcR = (const float*)d_in[11];
    const float* bfcR = (const float*)d_in[12];

    char* ws = (char*)d_ws;
    size_t off = 0;
    auto take = [&](size_t bytes) -> char* {
        off = (off + 255) & ~(size_t)255;
        char* p = ws + off;
        off += bytes;
        return p;
    };
    bf16*     WAH = (bf16*)take((size_t)2 * WA_UNITS_DIR * 1024);  // 6 MiB
    bf16*     WAL = (bf16*)take((size_t)2 * WA_UNITS_DIR * 1024);  // 6 MiB
    bf16*     WBH = (bf16*)take((size_t)2 * WB_UNITS_DIR * 1024);  // 8 MiB
    bf16*     WBL = (bf16*)take((size_t)2 * WB_UNITS_DIR * 1024);  // 8 MiB
    bf16*     WCH = (bf16*)take((size_t)2 * WC_UNITS_DIR * 1024);  // 0.5 MiB
    bf16*     WCL = (bf16*)take((size_t)2 * WC_UNITS_DIR * 1024);  // 0.5 MiB
    bf16*     H0  = (bf16*)take((size_t)8 * HPAR * 2);             // 2 MiB (dir x parity x hi/lo)
    bf16*     H1  = (bf16*)take((size_t)8 * HPAR * 2);             // 2 MiB
    float*    WCF = (float*)take((size_t)2 * 2048 * 512 * 4);      // 8 MiB fp32 scratch
    float*    BA  = (float*)take((size_t)2 * 2048 * 4);
    float*    BB  = (float*)take((size_t)2 * 2048 * 4);
    float*    BC  = (float*)take((size_t)2 * 256 * 4);
    unsigned* FLG = (unsigned*)take((size_t)(256 + 8) * 4);        // flags[256] + xcd cnt[8]

    hipMemsetAsync(H0, 0, (size_t)8 * HPAR * 2, stream);
    hipMemsetAsync(H1, 0, (size_t)8 * HPAR * 2, stream);
    hipMemsetAsync(FLG, 0, (size_t)(256 + 8) * 4, stream);         // clear flags + counters
    hipMemsetAsync(d_out, 0, (size_t)out_size * 4, stream);

    k_pack_wa<<<1536, 256, 0, stream>>>(wihL, whhL, wihR, whhR, WAH, WAL);
    k_wcomb  <<<8192, 256, 0, stream>>>(wihL, wfcL, wihR, wfcR, WCF);
    k_pack_wb<<<2048, 256, 0, stream>>>(whhL, whhR, WCF, WBH, WBL);
    k_pack_wc<<<128,  256, 0, stream>>>(wfcL, wfcR, WCH, WCL);
    k_bias   <<<16,   256, 0, stream>>>(bihL, bhhL, bfcL, wihL, bihR, bhhR, bfcR, wihR, BA, BB, BC);

    bilstm_main<<<256, 512, 0, stream>>>(x, WAH, WAL, WBH, WBL, WCH, WCL,
                                         H0, H1, BA, BB, BC, (float*)d_out, FLG);
}